// Round 2
// baseline (1175.143 us; speedup 1.0000x reference)
//
#include <hip/hip_runtime.h>
#include <hip/hip_bf16.h>

typedef unsigned int   u32;
typedef unsigned short u16;
typedef __attribute__((ext_vector_type(4))) float f32x4;
typedef __attribute__((ext_vector_type(8))) short short8;
typedef __attribute__((ext_vector_type(2))) u32   u32x2;

#define DM 1024
#define DF 4096
#define NE 8
#define NT 4096

__device__ __forceinline__ u32 cvt_pk_bf16(float lo, float hi) {
    u32 r;
    asm("v_cvt_pk_bf16_f32 %0, %1, %2" : "=v"(r) : "v"(lo), "v"(hi));
    return r;
}

__device__ __forceinline__ u16 f2bf(float f) {
    union { float f; u32 u; } v; v.f = f;
    u32 r = v.u + 0x7fffu + ((v.u >> 16) & 1u);
    return (u16)(r >> 16);
}

// ---------------- router: logits -> softmax -> top1 gate ----------------
__global__ __launch_bounds__(256)
void router_kernel(const float* __restrict__ x, const float* __restrict__ rW,
                   const float* __restrict__ rb, int* __restrict__ expert_of,
                   float* __restrict__ gate_of, int* __restrict__ counts) {
    const int lane = threadIdx.x & 63;
    const int tok  = blockIdx.x * 4 + (threadIdx.x >> 6);
    const float* xr = x + (size_t)tok * DM;
    float a[8];
#pragma unroll
    for (int e = 0; e < 8; ++e) a[e] = 0.f;
#pragma unroll
    for (int i = 0; i < 16; ++i) {
        const int d = i * 64 + lane;
        const float xd = xr[d];
        const f32x4 w0 = *(const f32x4*)(rW + d * 8);
        const f32x4 w1 = *(const f32x4*)(rW + d * 8 + 4);
        a[0] += xd * w0.x; a[1] += xd * w0.y; a[2] += xd * w0.z; a[3] += xd * w0.w;
        a[4] += xd * w1.x; a[5] += xd * w1.y; a[6] += xd * w1.z; a[7] += xd * w1.w;
    }
#pragma unroll
    for (int e = 0; e < 8; ++e) {
#pragma unroll
        for (int off = 32; off > 0; off >>= 1)
            a[e] += __shfl_xor(a[e], off);
    }
    if (lane == 0) {
        float mx = -1e30f; int am = 0;
#pragma unroll
        for (int e = 0; e < 8; ++e) {
            a[e] += rb[e];
            if (a[e] > mx) { mx = a[e]; am = e; }   // strict > keeps FIRST max (jnp.argmax)
        }
        float s = 0.f;
#pragma unroll
        for (int e = 0; e < 8; ++e) s += expf(a[e] - mx);
        expert_of[tok] = am;
        gate_of[tok]   = 1.0f / s;                  // p[argmax] = exp(0)/s
        atomicAdd(&counts[am], 1);
    }
}

__global__ void scan_kernel(const int* __restrict__ counts, int* __restrict__ offsets,
                            int* __restrict__ fill) {
    if (threadIdx.x == 0) {
        int o = 0;
        for (int e = 0; e < NE; ++e) { offsets[e] = o; fill[e] = o; o += counts[e]; }
    }
}

// ------------- gather: bucket tokens per expert, fp32 -> bf16 -------------
__global__ __launch_bounds__(256)
void gather_kernel(const float* __restrict__ x, const int* __restrict__ expert_of,
                   const float* __restrict__ gate_of, int* __restrict__ fill,
                   int* __restrict__ row2tok, float* __restrict__ gate_row,
                   u16* __restrict__ Abuf) {
    const int lane = threadIdx.x & 63;
    const int tok  = blockIdx.x * 4 + (threadIdx.x >> 6);
    int r = 0;
    if (lane == 0) {
        const int e = expert_of[tok];
        r = atomicAdd(&fill[e], 1);
        row2tok[r]  = tok;
        gate_row[r] = gate_of[tok];
    }
    r = __shfl(r, 0);
    const f32x4* src = (const f32x4*)(x + (size_t)tok * DM);
    u32x2* dst = (u32x2*)(Abuf + (size_t)r * DM);
#pragma unroll
    for (int i = 0; i < 4; ++i) {
        f32x4 v = src[i * 64 + lane];
        u32x2 p;
        p.x = cvt_pk_bf16(v.x, v.y);
        p.y = cvt_pk_bf16(v.z, v.w);
        dst[i * 64 + lane] = p;
    }
}

// ---------------- grouped GEMM, 128x128 tile, BK=32 ----------------
// A: bf16 [rows][K] (gathered, padded). B: fp32 [K][N] (weights, converted
// on the fly). Bs stored transposed [n][k] with XOR k-swizzle.
// IS2=false: C=relu(A*B+b1) -> bf16 H.  IS2=true: C=(A*B+b2)*gate scattered fp32.
template<int K, int N, bool IS2>
__global__ __launch_bounds__(256, 2)
void gemm_kernel(const u16* __restrict__ A, const float* __restrict__ Bg,
                 const float* __restrict__ biasg, void* __restrict__ Cv,
                 const int* __restrict__ counts, const int* __restrict__ offsets,
                 const int* __restrict__ row2tok, const float* __restrict__ gate_row) {
    const int e  = blockIdx.z;
    const int Me = counts[e];
    const int m0 = blockIdx.x * 128;
    if (m0 >= Me) return;
    const int n0   = blockIdx.y * 128;
    const int row0 = offsets[e];
    const float* B    = Bg + (size_t)e * K * N;
    const float* bias = biasg + e * N;

    __shared__ alignas(16) u16 As[128 * 32];
    __shared__ alignas(16) u16 Bs[128 * 32];
    u32* Bs32 = (u32*)Bs;

    const int tid  = threadIdx.x;
    const int lane = tid & 63;
    const int wid  = tid >> 6;
    const int wr   = (wid >> 1) * 64;
    const int wc   = (wid & 1) * 64;
    const int l15  = lane & 15;
    const int q    = lane >> 4;

    // B staging coords: thread covers rows (bk2, bk2+1), cols bn..bn+7
    const int bk2 = (tid >> 4) * 2;
    const int bn  = (tid & 15) * 8;
    const int kkw = (bk2 >> 1) ^ (((bn >> 4) & 3) << 2);  // swizzled dword idx

    // A staging coords (global_load_lds, 16B/lane, linear LDS)
    const int arow = tid >> 2;
    const int akb  = (tid & 3) * 16;
    const u16* Abase = A + (size_t)(row0 + m0) * K;
    const char* asrc0 = (const char*)(Abase + (size_t)arow * K) + akb;
    const char* asrc1 = (const char*)(Abase + (size_t)(64 + arow) * K) + akb;
    char* adst0 = (char*)As + (wid * 64) * 16;
    char* adst1 = (char*)As + (256 + wid * 64) * 16;

    f32x4 acc[4][4] = {};

    // prologue: B regs for k0 = 0
    const float* bp = B + (size_t)bk2 * N + n0 + bn;
    f32x4 c00 = *(const f32x4*)(bp);
    f32x4 c01 = *(const f32x4*)(bp + 4);
    f32x4 c10 = *(const f32x4*)(bp + N);
    f32x4 c11 = *(const f32x4*)(bp + N + 4);

    for (int k0 = 0; k0 < K; k0 += 32) {
        // async A -> LDS for this step (latency hidden under B cvt/ds_writes)
        __builtin_amdgcn_global_load_lds(
            (const __attribute__((address_space(1))) void*)(asrc0 + k0 * 2),
            (__attribute__((address_space(3))) void*)adst0, 16, 0, 0);
        __builtin_amdgcn_global_load_lds(
            (const __attribute__((address_space(1))) void*)(asrc1 + k0 * 2),
            (__attribute__((address_space(3))) void*)adst1, 16, 0, 0);
        // convert current B regs, write transposed+swizzled
        {
            u32 p0 = cvt_pk_bf16(c00.x, c10.x);
            u32 p1 = cvt_pk_bf16(c00.y, c10.y);
            u32 p2 = cvt_pk_bf16(c00.z, c10.z);
            u32 p3 = cvt_pk_bf16(c00.w, c10.w);
            u32 p4 = cvt_pk_bf16(c01.x, c11.x);
            u32 p5 = cvt_pk_bf16(c01.y, c11.y);
            u32 p6 = cvt_pk_bf16(c01.z, c11.z);
            u32 p7 = cvt_pk_bf16(c01.w, c11.w);
            Bs32[(bn + 0) * 16 + kkw] = p0;
            Bs32[(bn + 1) * 16 + kkw] = p1;
            Bs32[(bn + 2) * 16 + kkw] = p2;
            Bs32[(bn + 3) * 16 + kkw] = p3;
            Bs32[(bn + 4) * 16 + kkw] = p4;
            Bs32[(bn + 5) * 16 + kkw] = p5;
            Bs32[(bn + 6) * 16 + kkw] = p6;
            Bs32[(bn + 7) * 16 + kkw] = p7;
        }
        __syncthreads();   // drains vmcnt (A in LDS) + lgkm (B writes)
        // prefetch next-step B regs; latency hides under ds_reads + MFMA
        if (k0 + 32 < K) {
            const float* bq = B + (size_t)(k0 + 32 + bk2) * N + n0 + bn;
            c00 = *(const f32x4*)(bq);
            c01 = *(const f32x4*)(bq + 4);
            c10 = *(const f32x4*)(bq + N);
            c11 = *(const f32x4*)(bq + N + 4);
        }
        short8 af[4], bfr[4];
#pragma unroll
        for (int i = 0; i < 4; ++i)
            af[i] = *(const short8*)(As + (wr + i * 16 + l15) * 32 + q * 8);
#pragma unroll
        for (int j = 0; j < 4; ++j) {
            const int n  = wc + j * 16 + l15;
            const int qq = q ^ ((n >> 4) & 3);
            bfr[j] = *(const short8*)(Bs + n * 32 + qq * 8);
        }
#pragma unroll
        for (int i = 0; i < 4; ++i)
#pragma unroll
            for (int j = 0; j < 4; ++j)
                acc[i][j] = __builtin_amdgcn_mfma_f32_16x16x32_bf16(af[i], bfr[j], acc[i][j], 0, 0, 0);
        __syncthreads();   // protect LDS before next staging
    }

    if constexpr (!IS2) {
        u16* H = (u16*)Cv;
#pragma unroll
        for (int i = 0; i < 4; ++i) {
            const int r0 = m0 + wr + i * 16 + q * 4;
#pragma unroll
            for (int j = 0; j < 4; ++j) {
                const int gc = n0 + wc + j * 16 + l15;
                const float bb = bias[gc];
#pragma unroll
                for (int r = 0; r < 4; ++r) {
                    const int gr = r0 + r;
                    if (gr < Me) {
                        float v = fmaxf(acc[i][j][r] + bb, 0.0f);
                        H[(size_t)(row0 + gr) * N + gc] = f2bf(v);
                    }
                }
            }
        }
    } else {
        float* O = (float*)Cv;
#pragma unroll
        for (int i = 0; i < 4; ++i) {
            const int r0 = m0 + wr + i * 16 + q * 4;
            int   toks[4]; float gts[4];
#pragma unroll
            for (int r = 0; r < 4; ++r) {
                const int gr = r0 + r;
                const bool ok = gr < Me;
                toks[r] = ok ? row2tok[row0 + gr] : -1;
                gts[r]  = ok ? gate_row[row0 + gr] : 0.f;
            }
#pragma unroll
            for (int j = 0; j < 4; ++j) {
                const int gc = n0 + wc + j * 16 + l15;
                const float bb = bias[gc];
#pragma unroll
                for (int r = 0; r < 4; ++r) {
                    if (toks[r] >= 0)
                        O[(size_t)toks[r] * N + gc] = (acc[i][j][r] + bb) * gts[r];
                }
            }
        }
    }
}

extern "C" void kernel_launch(void* const* d_in, const int* in_sizes, int n_in,
                              void* d_out, int out_size, void* d_ws, size_t ws_size,
                              hipStream_t stream) {
    const float* x  = (const float*)d_in[0];
    const float* rW = (const float*)d_in[1];
    const float* rb = (const float*)d_in[2];
    const float* W1 = (const float*)d_in[3];
    const float* b1 = (const float*)d_in[4];
    const float* W2 = (const float*)d_in[5];
    const float* b2 = (const float*)d_in[6];
    float* out = (float*)d_out;

    char* ws = (char*)d_ws;
    int*   counts    = (int*)(ws + 0);
    int*   offsets   = (int*)(ws + 64);
    int*   fill      = (int*)(ws + 128);
    int*   expert_of = (int*)(ws + 256);
    float* gate_of   = (float*)(ws + 256 + 16384);
    int*   row2tok   = (int*)(ws + 256 + 32768);
    float* gate_row  = (float*)(ws + 256 + 49152);
    u16*   Abuf      = (u16*)(ws + 65792);                                   // (4096+128) x 1024 bf16
    u16*   Hbuf      = (u16*)(ws + 65792 + (size_t)(NT + 128) * DM * 2);     // (4096+128) x 4096 bf16

    // Workspace requirement: control (65792) + Abuf (8.65MB) + Hbuf (34.6MB).
    // If the harness workspace is smaller, bail cleanly (clear validation
    // failure) instead of corrupting device memory.
    const size_t REQUIRED = 65792ull
                          + (size_t)(NT + 128) * DM * 2ull
                          + (size_t)(NT + 128) * DF * 2ull;
    if (ws_size < REQUIRED) return;

    hipMemsetAsync(counts, 0, 64, stream);
    router_kernel<<<NT / 4, 256, 0, stream>>>(x, rW, rb, expert_of, gate_of, counts);
    scan_kernel<<<1, 64, 0, stream>>>(counts, offsets, fill);
    gather_kernel<<<NT / 4, 256, 0, stream>>>(x, expert_of, gate_of, fill, row2tok, gate_row, Abuf);
    gemm_kernel<DM, DF, false><<<dim3(32, 32, 8), 256, 0, stream>>>(
        Abuf, W1, b1, (void*)Hbuf, counts, offsets, nullptr, nullptr);
    gemm_kernel<DF, DM, true><<<dim3(32, 8, 8), 256, 0, stream>>>(
        Hbuf, W2, b2, (void*)out, counts, offsets, row2tok, gate_row);
}

// Round 4
// 582.679 us; speedup vs baseline: 2.0168x; 2.0168x over previous
//
#include <hip/hip_runtime.h>
#include <hip/hip_bf16.h>

typedef unsigned int   u32;
typedef unsigned short u16;
typedef __attribute__((ext_vector_type(4))) float f32x4;
typedef __attribute__((ext_vector_type(8))) short short8;
typedef __attribute__((ext_vector_type(2))) u32   u32x2;
typedef __attribute__((ext_vector_type(4))) u32   u32x4;

#define DM 1024
#define DF 4096
#define NE 8
#define NT 4096

__device__ __forceinline__ u32 cvt_pk_bf16(float lo, float hi) {
    u32 r;
    asm("v_cvt_pk_bf16_f32 %0, %1, %2" : "=v"(r) : "v"(lo), "v"(hi));
    return r;
}

__device__ __forceinline__ u16 f2bf(float f) {
    union { float f; u32 u; } v; v.f = f;
    u32 r = v.u + 0x7fffu + ((v.u >> 16) & 1u);
    return (u16)(r >> 16);
}

// ---------------- router: logits -> softmax -> top1 gate ----------------
__global__ __launch_bounds__(256)
void router_kernel(const float* __restrict__ x, const float* __restrict__ rW,
                   const float* __restrict__ rb, int* __restrict__ expert_of,
                   float* __restrict__ gate_of, int* __restrict__ counts) {
    const int lane = threadIdx.x & 63;
    const int tok  = blockIdx.x * 4 + (threadIdx.x >> 6);
    const float* xr = x + (size_t)tok * DM;
    float a[8];
#pragma unroll
    for (int e = 0; e < 8; ++e) a[e] = 0.f;
#pragma unroll
    for (int i = 0; i < 16; ++i) {
        const int d = i * 64 + lane;
        const float xd = xr[d];
        const f32x4 w0 = *(const f32x4*)(rW + d * 8);
        const f32x4 w1 = *(const f32x4*)(rW + d * 8 + 4);
        a[0] += xd * w0.x; a[1] += xd * w0.y; a[2] += xd * w0.z; a[3] += xd * w0.w;
        a[4] += xd * w1.x; a[5] += xd * w1.y; a[6] += xd * w1.z; a[7] += xd * w1.w;
    }
#pragma unroll
    for (int e = 0; e < 8; ++e) {
#pragma unroll
        for (int off = 32; off > 0; off >>= 1)
            a[e] += __shfl_xor(a[e], off);
    }
    if (lane == 0) {
        float mx = -1e30f; int am = 0;
#pragma unroll
        for (int e = 0; e < 8; ++e) {
            a[e] += rb[e];
            if (a[e] > mx) { mx = a[e]; am = e; }   // strict > keeps FIRST max (jnp.argmax)
        }
        float s = 0.f;
#pragma unroll
        for (int e = 0; e < 8; ++e) s += expf(a[e] - mx);
        expert_of[tok] = am;
        gate_of[tok]   = 1.0f / s;                  // p[argmax] = exp(0)/s
        atomicAdd(&counts[am], 1);
    }
}

__global__ void scan_kernel(const int* __restrict__ counts, int* __restrict__ offsets,
                            int* __restrict__ fill) {
    if (threadIdx.x == 0) {
        int o = 0;
        for (int e = 0; e < NE; ++e) { offsets[e] = o; fill[e] = o; o += counts[e]; }
    }
}

// ------------- gather: bucket tokens per expert, fp32 -> bf16 -------------
__global__ __launch_bounds__(256)
void gather_kernel(const float* __restrict__ x, const int* __restrict__ expert_of,
                   const float* __restrict__ gate_of, int* __restrict__ fill,
                   int* __restrict__ row2tok, float* __restrict__ gate_row,
                   u16* __restrict__ Abuf) {
    const int lane = threadIdx.x & 63;
    const int tok  = blockIdx.x * 4 + (threadIdx.x >> 6);
    int r = 0;
    if (lane == 0) {
        const int e = expert_of[tok];
        r = atomicAdd(&fill[e], 1);
        row2tok[r]  = tok;
        gate_row[r] = gate_of[tok];
    }
    r = __shfl(r, 0);
    const f32x4* src = (const f32x4*)(x + (size_t)tok * DM);
    u32x2* dst = (u32x2*)(Abuf + (size_t)r * DM);
#pragma unroll
    for (int i = 0; i < 4; ++i) {
        f32x4 v = src[i * 64 + lane];
        u32x2 p;
        p.x = cvt_pk_bf16(v.x, v.y);
        p.y = cvt_pk_bf16(v.z, v.w);
        dst[i * 64 + lane] = p;
    }
}

// -------- transpose-convert: W [E][K][N] fp32 -> Wt [E][N][K] bf16 --------
// 64x64 tiles through LDS; coalesced fp32 reads, 32B bf16 row-chunk writes.
// Store phase: nn = t>>2 in [0,64), kc = (t&3)*16 -> exact 64x64 coverage.
template<int K, int N>
__global__ __launch_bounds__(256)
void convt_kernel(const float* __restrict__ W, u16* __restrict__ Wt) {
    __shared__ float T[64][68];            // pad 68: rows 16B-aligned
    const int tpe = (K / 64) * (N / 64);
    int id = blockIdx.x;
    const int e = id / tpe; id -= e * tpe;
    const int k0 = (id / (N / 64)) * 64;
    const int n0 = (id % (N / 64)) * 64;
    const float* Wb = W + (size_t)e * K * N;
    u16* Wtb = Wt + (size_t)e * ((size_t)N * K);
    const int t = threadIdx.x;
    {
        const int r  = t >> 2;             // 0..63  (k within tile)
        const int cb = (t & 3) * 16;       // 0,16,32,48 (n within tile)
        const float* src = Wb + (size_t)(k0 + r) * N + n0 + cb;
        f32x4 v0 = *(const f32x4*)(src + 0);
        f32x4 v1 = *(const f32x4*)(src + 4);
        f32x4 v2 = *(const f32x4*)(src + 8);
        f32x4 v3 = *(const f32x4*)(src + 12);
        *(f32x4*)&T[r][cb + 0]  = v0;
        *(f32x4*)&T[r][cb + 4]  = v1;
        *(f32x4*)&T[r][cb + 8]  = v2;
        *(f32x4*)&T[r][cb + 12] = v3;
    }
    __syncthreads();
    {
        const int nn = t >> 2;             // 0..63  (n within tile)
        const int kc = (t & 3) * 16;       // 0,16,32,48 (k chunk base)
        u32x4 o0, o1;
#pragma unroll
        for (int j = 0; j < 4; ++j)
            o0[j] = cvt_pk_bf16(T[kc + 2*j][nn],     T[kc + 2*j + 1][nn]);
#pragma unroll
        for (int j = 0; j < 4; ++j)
            o1[j] = cvt_pk_bf16(T[kc + 8 + 2*j][nn], T[kc + 8 + 2*j + 1][nn]);
        u16* dst = Wtb + (size_t)(n0 + nn) * K + k0 + kc;
        *(u32x4*)(dst + 0) = o0;
        *(u32x4*)(dst + 8) = o1;
    }
}

// ---------------- grouped GEMM, m97 structure ----------------
// 128x128 tile, BK=32, both operands bf16 k-fast via global_load_lds(16B),
// linear LDS. 1-D grid, bijective XCD swizzle, expert-per-XCD chunking.
// A: [rows][K] bf16 (gathered). Wt: [E][N][K] bf16.
// IS2=false: relu(A*Wt^T + b1) -> bf16 H.  IS2=true: (A*Wt^T + b2)*gate -> fp32 scatter.
template<int K, int NBT, int MBT, bool IS2>
__global__ __launch_bounds__(256)
void gemm_kernel(const u16* __restrict__ A, const u16* __restrict__ Wt,
                 const float* __restrict__ biasg, void* __restrict__ Cv,
                 const int* __restrict__ counts, const int* __restrict__ offsets,
                 const int* __restrict__ row2tok, const float* __restrict__ gate_row) {
    constexpr int N = NBT * 128;
    constexpr int PER_XCD = MBT * NBT;     // one expert per XCD (NE == 8 == NXCD)
    const int bid = blockIdx.x;
    const int logical = (bid & 7) * PER_XCD + (bid >> 3);
    const int mb = logical % MBT;
    const int nb = (logical / MBT) % NBT;
    const int e  = logical / PER_XCD;

    const int Me = counts[e];
    const int m0 = mb * 128;
    if (m0 >= Me) return;
    const int n0   = nb * 128;
    const int row0 = offsets[e];
    const u16* Wte    = Wt + (size_t)e * ((size_t)N * K);
    const float* bias = biasg + e * N;

    __shared__ alignas(16) u16 As[128 * 32];
    __shared__ alignas(16) u16 Bs[128 * 32];

    const int tid  = threadIdx.x;
    const int lane = tid & 63;
    const int wid  = tid >> 6;
    const int wr   = (wid >> 1) * 64;
    const int wc   = (wid & 1) * 64;
    const int l15  = lane & 15;
    const int q    = lane >> 4;

    // staging: wave w stages rows [w*32, w*32+32); row=64B, 4 lanes/row
    const int srow  = wid * 32 + (lane >> 2);
    const int sbyte = (lane & 3) * 16;
    const u16* Ab = A + (size_t)(row0 + m0) * K;
    const char* asrc  = (const char*)(Ab + (size_t)srow * K) + sbyte;
    const char* asrc2 = (const char*)(Ab + (size_t)(srow + 16) * K) + sbyte;
    const char* bsrc  = (const char*)(Wte + (size_t)(n0 + srow) * K) + sbyte;
    const char* bsrc2 = (const char*)(Wte + (size_t)(n0 + srow + 16) * K) + sbyte;
    char* adst = (char*)As + wid * 2048 + lane * 16;
    char* bdst = (char*)Bs + wid * 2048 + lane * 16;

    f32x4 acc[4][4] = {};

    for (int k0 = 0; k0 < K; k0 += 32) {
        const int kb = k0 * 2;
        __builtin_amdgcn_global_load_lds(
            (const __attribute__((address_space(1))) void*)(asrc + kb),
            (__attribute__((address_space(3))) void*)adst, 16, 0, 0);
        __builtin_amdgcn_global_load_lds(
            (const __attribute__((address_space(1))) void*)(asrc2 + kb),
            (__attribute__((address_space(3))) void*)(adst + 1024), 16, 0, 0);
        __builtin_amdgcn_global_load_lds(
            (const __attribute__((address_space(1))) void*)(bsrc + kb),
            (__attribute__((address_space(3))) void*)bdst, 16, 0, 0);
        __builtin_amdgcn_global_load_lds(
            (const __attribute__((address_space(1))) void*)(bsrc2 + kb),
            (__attribute__((address_space(3))) void*)(bdst + 1024), 16, 0, 0);
        __syncthreads();
        short8 af[4], bf[4];
#pragma unroll
        for (int i = 0; i < 4; ++i)
            af[i] = *(const short8*)(As + (wr + i * 16 + l15) * 32 + q * 8);
#pragma unroll
        for (int j = 0; j < 4; ++j)
            bf[j] = *(const short8*)(Bs + (wc + j * 16 + l15) * 32 + q * 8);
#pragma unroll
        for (int i = 0; i < 4; ++i)
#pragma unroll
            for (int j = 0; j < 4; ++j)
                acc[i][j] = __builtin_amdgcn_mfma_f32_16x16x32_bf16(af[i], bf[j], acc[i][j], 0, 0, 0);
        __syncthreads();
    }

    if constexpr (!IS2) {
        u16* H = (u16*)Cv;
#pragma unroll
        for (int i = 0; i < 4; ++i) {
            const int r0 = m0 + wr + i * 16 + q * 4;
#pragma unroll
            for (int j = 0; j < 4; ++j) {
                const int gc = n0 + wc + j * 16 + l15;
                const float bb = bias[gc];
#pragma unroll
                for (int r = 0; r < 4; ++r) {
                    const int gr = r0 + r;
                    if (gr < Me) {
                        float v = fmaxf(acc[i][j][r] + bb, 0.0f);
                        H[(size_t)(row0 + gr) * N + gc] = f2bf(v);
                    }
                }
            }
        }
    } else {
        float* O = (float*)Cv;
#pragma unroll
        for (int i = 0; i < 4; ++i) {
            const int r0 = m0 + wr + i * 16 + q * 4;
            int   toks[4]; float gts[4];
#pragma unroll
            for (int r = 0; r < 4; ++r) {
                const int gr = r0 + r;
                const bool ok = gr < Me;
                toks[r] = ok ? row2tok[row0 + gr] : -1;
                gts[r]  = ok ? gate_row[row0 + gr] : 0.f;
            }
#pragma unroll
            for (int j = 0; j < 4; ++j) {
                const int gc = n0 + wc + j * 16 + l15;
                const float bb = bias[gc];
#pragma unroll
                for (int r = 0; r < 4; ++r) {
                    if (toks[r] >= 0)
                        O[(size_t)toks[r] * N + gc] = (acc[i][j][r] + bb) * gts[r];
                }
            }
        }
    }
}

extern "C" void kernel_launch(void* const* d_in, const int* in_sizes, int n_in,
                              void* d_out, int out_size, void* d_ws, size_t ws_size,
                              hipStream_t stream) {
    const float* x  = (const float*)d_in[0];
    const float* rW = (const float*)d_in[1];
    const float* rb = (const float*)d_in[2];
    const float* W1 = (const float*)d_in[3];
    const float* b1 = (const float*)d_in[4];
    const float* W2 = (const float*)d_in[5];
    const float* b2 = (const float*)d_in[6];
    float* out = (float*)d_out;

    char* ws = (char*)d_ws;
    int*   counts    = (int*)(ws + 0);
    int*   offsets   = (int*)(ws + 64);
    int*   fill      = (int*)(ws + 128);
    int*   expert_of = (int*)(ws + 256);
    float* gate_of   = (float*)(ws + 256 + 16384);
    int*   row2tok   = (int*)(ws + 256 + 32768);
    float* gate_row  = (float*)(ws + 256 + 49152);
    u16*   Abuf = (u16*)(ws + 65792);                                      // (4096+128) x 1024 bf16
    u16*   Hbuf = (u16*)(ws + 65792 + (size_t)(NT + 128) * DM * 2);        // (4096+128) x 4096 bf16
    u16*   Wt   = (u16*)(ws + 65792 + (size_t)(NT + 128) * DM * 2
                               + (size_t)(NT + 128) * DF * 2);             // 8x4096x1024 bf16 (shared W1t/W2t)

    const size_t REQUIRED = 65792ull
                          + (size_t)(NT + 128) * DM * 2ull
                          + (size_t)(NT + 128) * DF * 2ull
                          + (size_t)NE * DM * DF * 2ull;
    if (ws_size < REQUIRED) return;   // clean failure instead of corruption

    hipMemsetAsync(counts, 0, 64, stream);
    router_kernel<<<NT / 4, 256, 0, stream>>>(x, rW, rb, expert_of, gate_of, counts);
    scan_kernel<<<1, 64, 0, stream>>>(counts, offsets, fill);
    gather_kernel<<<NT / 4, 256, 0, stream>>>(x, expert_of, gate_of, fill, row2tok, gate_row, Abuf);

    // W1 [E][1024][4096] -> Wt [E][4096][1024], then FFN1
    convt_kernel<DM, DF><<<NE * (DM / 64) * (DF / 64), 256, 0, stream>>>(W1, Wt);
    gemm_kernel<DM, 32, 16, false><<<NE * 16 * 32, 256, 0, stream>>>(
        Abuf, Wt, b1, (void*)Hbuf, counts, offsets, nullptr, nullptr);

    // W2 [E][4096][1024] -> Wt [E][1024][4096] (reuse buffer; stream serializes), then FFN2
    convt_kernel<DF, DM><<<NE * (DF / 64) * (DM / 64), 256, 0, stream>>>(W2, Wt);
    gemm_kernel<DF, 8, 16, true><<<NE * 16 * 8, 256, 0, stream>>>(
        Hbuf, Wt, b2, (void*)out, counts, offsets, row2tok, gate_row);
}